// Round 13
// baseline (193.011 us; speedup 1.0000x reference)
//
#include <hip/hip_runtime.h>

#define BB 512
#define SS 512
#define TT 64
#define TSTRIDE 66   // transitions is (66,66)

typedef _Float16 h2 __attribute__((ext_vector_type(2)));
typedef int i2v __attribute__((ext_vector_type(2)));
typedef __attribute__((ext_vector_type(8))) short bf16x8;
typedef __attribute__((ext_vector_type(4))) float f32x4;
typedef __attribute__((ext_vector_type(4))) unsigned u32x4;

#define WS_VEC 0                       // F/U: 512*128 floats
#define WS_X   (BB * 128)              // X: 512*2*4096 floats
#define WS_DIFF (WS_X + BB * 2 * 4096) // diff: 512 floats

static __device__ __forceinline__ float first_lane(float v) {
    return __int_as_float(__builtin_amdgcn_readfirstlane(__float_as_int(v)));
}
static __device__ __forceinline__ unsigned pk_f16(float a, float b) {
    return __builtin_bit_cast(unsigned, __builtin_amdgcn_cvt_pkrtz(a, b));
}
static __device__ __forceinline__ h2 as_h2(unsigned u) {
    return __builtin_bit_cast(h2, u);
}
static __device__ __forceinline__ unsigned bperm(int addr, unsigned v) {
    return (unsigned)__builtin_amdgcn_ds_bpermute(addr, (int)v);
}
static __device__ __forceinline__ float swz16f(float v) {   // value from lane^16
    return __int_as_float(__builtin_amdgcn_ds_swizzle(__float_as_int(v), 0x401F));
}
static __device__ __forceinline__ unsigned pk_bf16(float a, float b) {
    unsigned r;
    asm("v_cvt_pk_bf16_f32 %0, %1, %2" : "=v"(r) : "v"(a), "v"(b));
    return r;
}
#define FDOT2(a, b, c) __builtin_amdgcn_fdot2((a), (b), (c), false)
#define DPPF(v, ctrl) __int_as_float(__builtin_amdgcn_mov_dpp(__float_as_int(v), (ctrl), 0xF, 0xF, true))
#define DPPU(v, ctrl) ((unsigned)__builtin_amdgcn_mov_dpp((int)(v), (ctrl), 0xF, 0xF, true))
#define MFMA16(A, B, C) __builtin_amdgcn_mfma_f32_16x16x32_bf16((A), (B), (C), 0, 0, 0)

#define DO32(F) F(0) F(1) F(2) F(3) F(4) F(5) F(6) F(7) \
                F(8) F(9) F(10) F(11) F(12) F(13) F(14) F(15) \
                F(16) F(17) F(18) F(19) F(20) F(21) F(22) F(23) \
                F(24) F(25) F(26) F(27) F(28) F(29) F(30) F(31)

// 4-segment MITM. Block 4b+role: role0 = fwd vec steps 1..127 -> F(pos127);
// role1 = bwd vec steps 511..384 -> U(pos383); role2 = matrix steps 128..255;
// role3 = matrix steps 256..383 (masked). Matrix: X' = D_g (E^T X) via
// 32x mfma 16x16x32 bf16/step; A/B layout k=4(l>>4)+(e&3)+16(e>>2) (per
// measured tr_b16 mapping), C layout col=l&15,row=4(l>>4)+reg (verified) =>
// C->B conversion is LANE-LOCAL (32 cvt_pk_bf16, no cross-lane).
// Per-step scale e^{-0.5}/64 (unmasked) or 1/64 (masked); exact log recovery
// in combine. 2048 waves = 2/SIMD: co-resident waves fill latency bubbles.
__global__ __launch_bounds__(64)
__attribute__((amdgpu_waves_per_eu(1, 2)))
void crf_scan4_kernel(
    const float* __restrict__ emissions,   // [B,S,T]
    const float* __restrict__ mask,        // [B,S]
    const float* __restrict__ trans,       // [66,66]
    float* __restrict__ ws)
{
    __shared__ unsigned EQ[32][64];

    const int blk  = blockIdx.x;
    const int b    = blk >> 2;
    const int role = blk & 3;
    const int j    = threadIdx.x;
    const bool lo32 = (j < 32);
    const int a32v = ((j ^ 32) << 2);

    const float* em = emissions + (size_t)b * SS * TT;
    const float* mk = mask + (size_t)b * SS;

    if (role < 2) {
        // ================= vector segments (R11 step skeleton) =============
        const int dir = role;
        {
            const int tl[8] = {0, 2, 7, 5, 15, 13, 8, 10};
            #pragma unroll
            for (int w = 0; w < 32; ++w) {
                int m = w >> 3, k = w & 7;
                int y0 = j ^ tl[k];
                int y1 = y0 ^ 1;
                int x  = j ^ (m << 4);
                if (dir == 0)
                    EQ[w][j] = pk_f16(__expf(trans[y0 * TSTRIDE + x]),
                                      __expf(trans[y1 * TSTRIDE + x]));
                else
                    EQ[w][j] = pk_f16(__expf(trans[x * TSTRIDE + y0]),
                                      __expf(trans[x * TSTRIDE + y1]));
            }
        }
        __syncthreads();

#define CDECL(K) const unsigned c##K = EQ[K][j];
        DO32(CDECL)
#undef CDECL

#if defined(__has_builtin) && __has_builtin(__builtin_amdgcn_permlane32_swap)
#define XCH32F(DST, SRC) { i2v r_ = __builtin_amdgcn_permlane32_swap( \
                               __float_as_int(SRC), __float_as_int(SRC), false, false); \
                           DST = __int_as_float(lo32 ? r_.y : r_.x); }
#else
#define XCH32F(DST, SRC) { DST = __int_as_float((int)bperm(a32v, (unsigned)__float_as_int(SRC))); }
#endif

#define STEPC(PRE, POST, CADD) do { \
        float m0c = first_lane(sc) + (CADD); \
        float p   = __expf(sc + (PRE) - m0c); \
        float pn_ = DPPF(p, 0xB1); \
        unsigned W0 = pk_f16(p, pn_); \
        unsigned W1 = DPPU(W0, 0x4E); \
        unsigned W2 = DPPU(W0, 0x141); \
        unsigned W3 = DPPU(W1, 0x141); \
        unsigned W4 = DPPU(W0, 0x140); \
        unsigned W5 = DPPU(W1, 0x140); \
        unsigned W6 = DPPU(W4, 0x141); \
        unsigned W7 = DPPU(W5, 0x141); \
        float a0_ = 0.f, a1_ = 0.f, a2_ = 0.f, a3_ = 0.f; \
        a0_ = FDOT2(as_h2(W0), as_h2(c0),  a0_); \
        a1_ = FDOT2(as_h2(W0), as_h2(c8),  a1_); \
        a2_ = FDOT2(as_h2(W0), as_h2(c16), a2_); \
        a3_ = FDOT2(as_h2(W0), as_h2(c24), a3_); \
        a0_ = FDOT2(as_h2(W1), as_h2(c1),  a0_); \
        a1_ = FDOT2(as_h2(W1), as_h2(c9),  a1_); \
        a2_ = FDOT2(as_h2(W1), as_h2(c17), a2_); \
        a3_ = FDOT2(as_h2(W1), as_h2(c25), a3_); \
        a0_ = FDOT2(as_h2(W2), as_h2(c2),  a0_); \
        a1_ = FDOT2(as_h2(W2), as_h2(c10), a1_); \
        a2_ = FDOT2(as_h2(W2), as_h2(c18), a2_); \
        a3_ = FDOT2(as_h2(W2), as_h2(c26), a3_); \
        a0_ = FDOT2(as_h2(W3), as_h2(c3),  a0_); \
        a1_ = FDOT2(as_h2(W3), as_h2(c11), a1_); \
        a2_ = FDOT2(as_h2(W3), as_h2(c19), a2_); \
        a3_ = FDOT2(as_h2(W3), as_h2(c27), a3_); \
        a0_ = FDOT2(as_h2(W4), as_h2(c4),  a0_); \
        a1_ = FDOT2(as_h2(W4), as_h2(c12), a1_); \
        a2_ = FDOT2(as_h2(W4), as_h2(c20), a2_); \
        a3_ = FDOT2(as_h2(W4), as_h2(c28), a3_); \
        a0_ = FDOT2(as_h2(W5), as_h2(c5),  a0_); \
        a1_ = FDOT2(as_h2(W5), as_h2(c13), a1_); \
        a2_ = FDOT2(as_h2(W5), as_h2(c21), a2_); \
        a3_ = FDOT2(as_h2(W5), as_h2(c29), a3_); \
        a0_ = FDOT2(as_h2(W6), as_h2(c6),  a0_); \
        a1_ = FDOT2(as_h2(W6), as_h2(c14), a1_); \
        a2_ = FDOT2(as_h2(W6), as_h2(c22), a2_); \
        a3_ = FDOT2(as_h2(W6), as_h2(c30), a3_); \
        a0_ = FDOT2(as_h2(W7), as_h2(c7),  a0_); \
        a1_ = FDOT2(as_h2(W7), as_h2(c15), a1_); \
        a2_ = FDOT2(as_h2(W7), as_h2(c23), a2_); \
        a3_ = FDOT2(as_h2(W7), as_h2(c31), a3_); \
        float V0 = a0_ + swz16f(a1_); \
        float V1 = a2_ + swz16f(a3_); \
        float Vx; XCH32F(Vx, V1); \
        float sum_ = V0 + Vx; \
        sc = m0c + __logf(sum_) + (POST); \
    } while (0)

        float sc;
        if (dir == 0) {
            // forward: steps 1..127 (always unmasked; len >= 256)
            sc = em[j] + trans[j * TSTRIDE + TT];
            float r0 = em[1 * TT + j], r1 = em[2 * TT + j];
            float r2 = em[3 * TT + j], r3 = em[4 * TT + j];
            float r4 = em[5 * TT + j], r5 = em[6 * TT + j];
            float r6 = em[7 * TT + j], r7 = em[8 * TT + j];
            const float* pe = em + 9 * TT + j;
            for (int it = 0; it < 15; ++it) {     // steps 1..120
                float n0 = pe[0],   n1 = pe[64],  n2 = pe[128], n3 = pe[192];
                float n4 = pe[256], n5 = pe[320], n6 = pe[384], n7 = pe[448];
                pe += 512;
                STEPC(0.0f, r0, 4.0f); STEPC(0.0f, r1, 4.0f);
                STEPC(0.0f, r2, 4.0f); STEPC(0.0f, r3, 4.0f);
                STEPC(0.0f, r4, 4.0f); STEPC(0.0f, r5, 4.0f);
                STEPC(0.0f, r6, 4.0f); STEPC(0.0f, r7, 4.0f);
                r0 = n0; r1 = n1; r2 = n2; r3 = n3;
                r4 = n4; r5 = n5; r6 = n6; r7 = n7;
            }
            STEPC(0.0f, r0, 4.0f); STEPC(0.0f, r1, 4.0f);   // 121..127
            STEPC(0.0f, r2, 4.0f); STEPC(0.0f, r3, 4.0f);
            STEPC(0.0f, r4, 4.0f); STEPC(0.0f, r5, 4.0f);
            STEPC(0.0f, r6, 4.0f);
            ws[(size_t)b * 128 + j] = sc;
        } else {
            // backward: steps 511..384
            float msum = 0.f;
            #pragma unroll
            for (int t = 0; t < 8; ++t) msum += mk[j + 64 * t];
            #pragma unroll
            for (int off = 32; off; off >>= 1) msum += __shfl_xor(msum, off);
            const int len = (int)(first_lane(msum) + 0.5f);

            sc = trans[65 * TSTRIDE + j];
            float r0 = em[511 * TT + j], r1 = em[510 * TT + j];
            float r2 = em[509 * TT + j], r3 = em[508 * TT + j];
            float r4 = em[507 * TT + j], r5 = em[506 * TT + j];
            float r6 = em[505 * TT + j], r7 = em[504 * TT + j];
            const float* pe = em + 503 * TT + j;
            int scur = 511;
#define BEE(RK, SV) (((SV) < len) ? (RK) : 0.0f)
            for (int it = 0; it < 15; ++it) {     // steps 511..392
                float n0 = pe[0],    n1 = pe[-64],  n2 = pe[-128], n3 = pe[-192];
                float n4 = pe[-256], n5 = pe[-320], n6 = pe[-384], n7 = pe[-448];
                pe -= 512;
                STEPC(BEE(r0, scur - 0), 0.0f, 5.0f);
                STEPC(BEE(r1, scur - 1), 0.0f, 5.0f);
                STEPC(BEE(r2, scur - 2), 0.0f, 5.0f);
                STEPC(BEE(r3, scur - 3), 0.0f, 5.0f);
                STEPC(BEE(r4, scur - 4), 0.0f, 5.0f);
                STEPC(BEE(r5, scur - 5), 0.0f, 5.0f);
                STEPC(BEE(r6, scur - 6), 0.0f, 5.0f);
                STEPC(BEE(r7, scur - 7), 0.0f, 5.0f);
                scur -= 8;
                r0 = n0; r1 = n1; r2 = n2; r3 = n3;
                r4 = n4; r5 = n5; r6 = n6; r7 = n7;
            }
            STEPC(BEE(r0, 391), 0.0f, 5.0f); STEPC(BEE(r1, 390), 0.0f, 5.0f);
            STEPC(BEE(r2, 389), 0.0f, 5.0f); STEPC(BEE(r3, 388), 0.0f, 5.0f);
            STEPC(BEE(r4, 387), 0.0f, 5.0f); STEPC(BEE(r5, 386), 0.0f, 5.0f);
            STEPC(BEE(r6, 385), 0.0f, 5.0f); STEPC(BEE(r7, 384), 0.0f, 5.0f);
#undef BEE
            ws[(size_t)b * 128 + 64 + j] = sc;
        }
#undef STEPC
#undef XCH32F
    } else {
        // ===================== matrix segments =============================
        const int g4  = j >> 4;
        const int c15 = j & 15;
        const int lo  = (role == 2) ? 128 : 256;
        const int hi  = lo + 128;
        const f32x4 ZERO4 = {0.f, 0.f, 0.f, 0.f};

        int lenEff = SS;
        if (role == 3) {
            float msum = 0.f;
            #pragma unroll
            for (int t = 0; t < 8; ++t) msum += mk[j + 64 * t];
            #pragma unroll
            for (int off = 32; off; off >>= 1) msum += __shfl_xor(msum, off);
            lenEff = (int)(first_lane(msum) + 0.5f);
        }

        // A fragments: A[m][k] = E^T[m][k] = exp(tt[k][m]);
        // m = 16tr + c15, k = 32kc + 16(w>>1) + 4g4 + 2(w&1) (+1 for hi elem)
#define AWORD(TR, KC, W) ({ \
        int k_ = 32*(KC) + 16*((W)>>1) + 4*g4 + 2*((W)&1); \
        int m_ = 16*(TR) + c15; \
        pk_bf16(__expf(trans[k_ * TSTRIDE + m_]), \
                __expf(trans[(k_ + 1) * TSTRIDE + m_])); })
#define MKA(TR, KC) __builtin_bit_cast(bf16x8, (u32x4){ \
        AWORD(TR, KC, 0), AWORD(TR, KC, 1), AWORD(TR, KC, 2), AWORD(TR, KC, 3)})
        const bf16x8 A00 = MKA(0,0), A01 = MKA(0,1);
        const bf16x8 A10 = MKA(1,0), A11 = MKA(1,1);
        const bf16x8 A20 = MKA(2,0), A21 = MKA(2,1);
        const bf16x8 A30 = MKA(3,0), A31 = MKA(3,1);
#undef MKA
#undef AWORD

        // B init = Identity (bf16 1.0 = 0x3F80)
#define IWORD(TC, KC, W) ({ \
        int k_ = 32*(KC) + 16*((W)>>1) + 4*g4 + 2*((W)&1); \
        int col_ = 16*(TC) + c15; \
        (unsigned)(((k_ == col_) ? 0x3F80u : 0u) | \
                   (((k_ + 1 == col_) ? 0x3F80u : 0u) << 16)); })
#define MKI(TC, KC) __builtin_bit_cast(bf16x8, (u32x4){ \
        IWORD(TC, KC, 0), IWORD(TC, KC, 1), IWORD(TC, KC, 2), IWORD(TC, KC, 3)})
        bf16x8 B00 = MKI(0,0), B01 = MKI(0,1);
        bf16x8 B10 = MKI(1,0), B11 = MKI(1,1);
        bf16x8 B20 = MKI(2,0), B21 = MKI(2,1);
        bf16x8 B30 = MKI(3,0), B31 = MKI(3,1);
#undef MKI
#undef IWORD

        // emission prefetch for step lo
        const float* ge = em + (size_t)lo * TT + 4 * g4;
        float n00 = ge[0],  n01 = ge[1],  n02 = ge[2],  n03 = ge[3];
        float n10 = ge[16], n11 = ge[17], n12 = ge[18], n13 = ge[19];
        float n20 = ge[32], n21 = ge[33], n22 = ge[34], n23 = ge[35];
        float n30 = ge[48], n31 = ge[49], n32 = ge[50], n33 = ge[51];
        ge += TT;

#define GCOMP(UM) \
        float G00 = (UM) ? __expf(n00 - 0.5f) * 0.015625f : 0.015625f; \
        float G01 = (UM) ? __expf(n01 - 0.5f) * 0.015625f : 0.015625f; \
        float G02 = (UM) ? __expf(n02 - 0.5f) * 0.015625f : 0.015625f; \
        float G03 = (UM) ? __expf(n03 - 0.5f) * 0.015625f : 0.015625f; \
        float G10 = (UM) ? __expf(n10 - 0.5f) * 0.015625f : 0.015625f; \
        float G11 = (UM) ? __expf(n11 - 0.5f) * 0.015625f : 0.015625f; \
        float G12 = (UM) ? __expf(n12 - 0.5f) * 0.015625f : 0.015625f; \
        float G13 = (UM) ? __expf(n13 - 0.5f) * 0.015625f : 0.015625f; \
        float G20 = (UM) ? __expf(n20 - 0.5f) * 0.015625f : 0.015625f; \
        float G21 = (UM) ? __expf(n21 - 0.5f) * 0.015625f : 0.015625f; \
        float G22 = (UM) ? __expf(n22 - 0.5f) * 0.015625f : 0.015625f; \
        float G23 = (UM) ? __expf(n23 - 0.5f) * 0.015625f : 0.015625f; \
        float G30 = (UM) ? __expf(n30 - 0.5f) * 0.015625f : 0.015625f; \
        float G31 = (UM) ? __expf(n31 - 0.5f) * 0.015625f : 0.015625f; \
        float G32 = (UM) ? __expf(n32 - 0.5f) * 0.015625f : 0.015625f; \
        float G33 = (UM) ? __expf(n33 - 0.5f) * 0.015625f : 0.015625f;

#define NLOAD \
        n00 = ge[0];  n01 = ge[1];  n02 = ge[2];  n03 = ge[3];  \
        n10 = ge[16]; n11 = ge[17]; n12 = ge[18]; n13 = ge[19]; \
        n20 = ge[32]; n21 = ge[33]; n22 = ge[34]; n23 = ge[35]; \
        n30 = ge[48]; n31 = ge[49]; n32 = ge[50]; n33 = ge[51]; \
        ge += TT;

#define TILE(TR, TC) \
        f32x4 c##TR##TC = MFMA16(A##TR##0, B##TC##0, ZERO4); \
        c##TR##TC = MFMA16(A##TR##1, B##TC##1, c##TR##TC); \
        c##TR##TC[0] *= G##TR##0; c##TR##TC[1] *= G##TR##1; \
        c##TR##TC[2] *= G##TR##2; c##TR##TC[3] *= G##TR##3;

#define BSET(TC, KC, TA, TB) \
        B##TC##KC = __builtin_bit_cast(bf16x8, (u32x4){ \
            pk_bf16(c##TA##TC[0], c##TA##TC[1]), \
            pk_bf16(c##TA##TC[2], c##TA##TC[3]), \
            pk_bf16(c##TB##TC[0], c##TB##TC[1]), \
            pk_bf16(c##TB##TC[2], c##TB##TC[3]) });

        for (int s = lo; s < hi - 1; ++s) {
            const bool um = (s < lenEff);
            GCOMP(um)
            NLOAD
            TILE(0,0) TILE(0,1) TILE(0,2) TILE(0,3)
            TILE(1,0) TILE(1,1) TILE(1,2) TILE(1,3)
            TILE(2,0) TILE(2,1) TILE(2,2) TILE(2,3)
            TILE(3,0) TILE(3,1) TILE(3,2) TILE(3,3)
            BSET(0,0,0,1) BSET(0,1,2,3)
            BSET(1,0,0,1) BSET(1,1,2,3)
            BSET(2,0,0,1) BSET(2,1,2,3)
            BSET(3,0,0,1) BSET(3,1,2,3)
        }
        {   // final step: scale then STORE (no pack)
            const int s = hi - 1;
            const bool um = (s < lenEff);
            GCOMP(um)
            TILE(0,0) TILE(0,1) TILE(0,2) TILE(0,3)
            TILE(1,0) TILE(1,1) TILE(1,2) TILE(1,3)
            TILE(2,0) TILE(2,1) TILE(2,2) TILE(2,3)
            TILE(3,0) TILE(3,1) TILE(3,2) TILE(3,3)
            float* Xo = ws + WS_X + (size_t)b * 8192 + (role == 3 ? 4096 : 0);
#define XSTORE(TR, TC) \
            Xo[(16*(TR) + 4*g4 + 0) * 64 + 16*(TC) + c15] = c##TR##TC[0]; \
            Xo[(16*(TR) + 4*g4 + 1) * 64 + 16*(TC) + c15] = c##TR##TC[1]; \
            Xo[(16*(TR) + 4*g4 + 2) * 64 + 16*(TC) + c15] = c##TR##TC[2]; \
            Xo[(16*(TR) + 4*g4 + 3) * 64 + 16*(TC) + c15] = c##TR##TC[3];
            XSTORE(0,0) XSTORE(0,1) XSTORE(0,2) XSTORE(0,3)
            XSTORE(1,0) XSTORE(1,1) XSTORE(1,2) XSTORE(1,3)
            XSTORE(2,0) XSTORE(2,1) XSTORE(2,2) XSTORE(2,3)
            XSTORE(3,0) XSTORE(3,1) XSTORE(3,2) XSTORE(3,3)
#undef XSTORE
        }
#undef BSET
#undef TILE
#undef NLOAD
#undef GCOMP
    }
}

// Per-batch: p127 = exp(F-aF); q = XA p; r = XB (q/q0); logZ = LSE(ln r + U)
// + anchors + exact scale constants. Plus gold path.
__global__ __launch_bounds__(64) void crf_combine_kernel(
    const float* __restrict__ emissions,
    const int*   __restrict__ tags,
    const float* __restrict__ mask,
    const float* __restrict__ trans,
    const float* __restrict__ ws,
    float* __restrict__ diff_out)
{
    __shared__ float PS[64], PS2[64];
    const int b = blockIdx.x;
    const int j = threadIdx.x;
    const float* em = emissions + (size_t)b * SS * TT;
    const float* mk = mask + (size_t)b * SS;

    const float F = ws[(size_t)b * 128 + j];
    const float U = ws[(size_t)b * 128 + 64 + j];
    const float aF = first_lane(F) + 4.0f;
    PS[j] = __expf(F - aF);
    __syncthreads();

    const float* XA = ws + WS_X + (size_t)b * 8192;
    const float* XB = XA + 4096;

    float q = 0.f;
    {
        const f32x4* row = (const f32x4*)(XA + (size_t)j * 64);
        #pragma unroll
        for (int i = 0; i < 16; ++i) {
            f32x4 x = row[i];
            q += x[0] * PS[4*i] + x[1] * PS[4*i+1] + x[2] * PS[4*i+2] + x[3] * PS[4*i+3];
        }
    }
    const float q0 = first_lane(q);
    const float lnq = __logf(q0);
    PS2[j] = q / q0;
    __syncthreads();

    float r = 0.f;
    {
        const f32x4* row = (const f32x4*)(XB + (size_t)j * 64);
        #pragma unroll
        for (int i = 0; i < 16; ++i) {
            f32x4 x = row[i];
            r += x[0] * PS2[4*i] + x[1] * PS2[4*i+1] + x[2] * PS2[4*i+2] + x[3] * PS2[4*i+3];
        }
    }

    // len
    float msum = 0.f;
    #pragma unroll
    for (int t = 0; t < 8; ++t) msum += mk[j + 64 * t];
    #pragma unroll
    for (int off = 32; off; off >>= 1) msum += __shfl_xor(msum, off);
    const int len = (int)(first_lane(msum) + 0.5f);

    // logZ
    float t_ = __logf(r) + U;
    float m = t_;
    #pragma unroll
    for (int off = 32; off; off >>= 1) m = fmaxf(m, __shfl_xor(m, off));
    float e = __expf(t_ - m);
    #pragma unroll
    for (int off = 32; off; off >>= 1) e += __shfl_xor(e, off);
    const float LN64 = 4.1588830833596715f;
    int lenB = len - 256; lenB = lenB < 0 ? 0 : (lenB > 128 ? 128 : lenB);
    float zres = m + __logf(e) + lnq + aF
               + 128.0f * (LN64 + 0.5f)            // segment A scale
               + 128.0f * LN64 + 0.5f * (float)lenB; // segment B scale

    // gold
    const int* tg = tags + (size_t)b * SS;
    float acc = 0.f;
    for (int s = j; s < SS; s += 64) {
        if (s < len) {
            if (s > 0) {
                int curr = tg[s], prev = tg[s - 1];
                acc += trans[curr * TSTRIDE + prev] + em[s * TT + curr];
            } else {
                int t0_ = tg[0];
                acc += em[t0_] + trans[t0_ * TSTRIDE + TT];
            }
        }
    }
    #pragma unroll
    for (int off = 32; off; off >>= 1) acc += __shfl_xor(acc, off);
    if (j == 0) {
        int last = tg[len - 1];
        acc += trans[65 * TSTRIDE + last];
        diff_out[b] = zres - acc;
    }
}

__global__ __launch_bounds__(256) void crf_final_kernel(
    const float* __restrict__ diff,
    float* __restrict__ out)
{
    __shared__ float sdata[4];
    int t = threadIdx.x;
    float v = 0.f;
    for (int i = t; i < BB; i += 256) v += diff[i];
    #pragma unroll
    for (int off = 32; off; off >>= 1) v += __shfl_xor(v, off);
    if ((t & 63) == 0) sdata[t >> 6] = v;
    __syncthreads();
    if (t == 0) out[0] = (sdata[0] + sdata[1] + sdata[2] + sdata[3]) * (1.0f / BB);
}

extern "C" void kernel_launch(void* const* d_in, const int* in_sizes, int n_in,
                              void* d_out, int out_size, void* d_ws, size_t ws_size,
                              hipStream_t stream) {
    const float* emissions = (const float*)d_in[0];
    const int*   tags      = (const int*)d_in[1];
    const float* mask      = (const float*)d_in[2];
    const float* trans     = (const float*)d_in[3];
    float* out  = (float*)d_out;
    float* ws   = (float*)d_ws;   // needs (512*128 + 512*8192 + 512)*4B ~= 17.3 MB
    float* diff = ws + WS_DIFF;

    crf_scan4_kernel<<<4 * BB, 64, 0, stream>>>(emissions, mask, trans, ws);
    crf_combine_kernel<<<BB, 64, 0, stream>>>(emissions, tags, mask, trans, ws, diff);
    crf_final_kernel<<<1, 256, 0, stream>>>(diff, out);
}

// Round 14
// 102.259 us; speedup vs baseline: 1.8875x; 1.8875x over previous
//
#include <hip/hip_runtime.h>

#define BB 512
#define SS 512
#define TT 64
#define TSTRIDE 66   // transitions is (66,66)

typedef _Float16 h2 __attribute__((ext_vector_type(2)));
typedef int i2v __attribute__((ext_vector_type(2)));

static __device__ __forceinline__ float first_lane(float v) {
    return __int_as_float(__builtin_amdgcn_readfirstlane(__float_as_int(v)));
}
static __device__ __forceinline__ unsigned pk_f16(float a, float b) {
    return __builtin_bit_cast(unsigned, __builtin_amdgcn_cvt_pkrtz(a, b));
}
static __device__ __forceinline__ h2 as_h2(unsigned u) {
    return __builtin_bit_cast(h2, u);
}
static __device__ __forceinline__ unsigned bperm(int addr, unsigned v) {
    return (unsigned)__builtin_amdgcn_ds_bpermute(addr, (int)v);
}
static __device__ __forceinline__ float swz16f(float v) {   // value from lane^16
    return __int_as_float(__builtin_amdgcn_ds_swizzle(__float_as_int(v), 0x401F));
}
#define FDOT2(a, b, c) __builtin_amdgcn_fdot2((a), (b), (c), false)
#define DPPF(v, ctrl) __int_as_float(__builtin_amdgcn_mov_dpp(__float_as_int(v), (ctrl), 0xF, 0xF, true))
#define DPPU(v, ctrl) ((unsigned)__builtin_amdgcn_mov_dpp((int)(v), (ctrl), 0xF, 0xF, true))

#define DO32(F) F(0) F(1) F(2) F(3) F(4) F(5) F(6) F(7) \
                F(8) F(9) F(10) F(11) F(12) F(13) F(14) F(15) \
                F(16) F(17) F(18) F(19) F(20) F(21) F(22) F(23) \
                F(24) F(25) F(26) F(27) F(28) F(29) F(30) F(31)

// R14: DUAL-CHAIN wave. One wave per batch runs BOTH the forward chain
// (steps 1..255) and the backward chain (steps 511..256), interleaved in the
// instruction stream. The two chains are independent -> the scheduler fills
// each chain's dependent-latency bubbles (~500cy/step exposed at 1 wave/SIMD,
// R11 finding) with the other chain's instructions. Step skeleton = R11's
// blocked matvec (absmax-0 verified): DPP tree W_k = {p[j^tl_k], p[j^tl_k^1]},
// tl={0,2,7,5,15,13,8,10}; 4 col-partials; reduce via 2x ds_swizzle(^16) +
// permlane32_swap(^32).
__global__ __launch_bounds__(64)
__attribute__((amdgpu_waves_per_eu(1, 1)))
void crf_scan_dual_kernel(
    const float* __restrict__ emissions,   // [B,S,T]
    const float* __restrict__ mask,        // [B,S]
    const float* __restrict__ trans,       // [66,66]
    float* __restrict__ ws_state)          // [B][128]: F[64] then U[64]
{
    __shared__ unsigned EQ[32][64];

    const int b = blockIdx.x;
    const int j = threadIdx.x;   // 0..63
    const bool lo32 = (j < 32);
    const int a32v = ((j ^ 32) << 2);

    const float* em = emissions + (size_t)b * SS * TT;
    const float* mk = mask + (size_t)b * SS;

    const int tl[8] = {0, 2, 7, 5, 15, 13, 8, 10};

    // ---- forward E table (M[x][y] = trans[y*66+x]) ----
    #pragma unroll
    for (int w = 0; w < 32; ++w) {
        int m = w >> 3, k = w & 7;
        int y0 = j ^ tl[k];
        int x  = j ^ (m << 4);
        EQ[w][j] = pk_f16(__expf(trans[y0 * TSTRIDE + x]),
                          __expf(trans[(y0 ^ 1) * TSTRIDE + x]));
    }
    __syncthreads();
#define CDECLF(K) const unsigned cF##K = EQ[K][j];
    DO32(CDECLF)
#undef CDECLF
    __syncthreads();

    // ---- backward E table (M[x][y] = trans[x*66+y]) ----
    #pragma unroll
    for (int w = 0; w < 32; ++w) {
        int m = w >> 3, k = w & 7;
        int y0 = j ^ tl[k];
        int x  = j ^ (m << 4);
        EQ[w][j] = pk_f16(__expf(trans[x * TSTRIDE + y0]),
                          __expf(trans[x * TSTRIDE + (y0 ^ 1)]));
    }
    __syncthreads();
#define CDECLB(K) const unsigned cB##K = EQ[K][j];
    DO32(CDECLB)
#undef CDECLB

#if defined(__has_builtin) && __has_builtin(__builtin_amdgcn_permlane32_swap)
#define XCH32F(DST, SRC) { i2v r_ = __builtin_amdgcn_permlane32_swap( \
                               __float_as_int(SRC), __float_as_int(SRC), false, false); \
                           DST = __int_as_float(lo32 ? r_.y : r_.x); }
#else
#define XCH32F(DST, SRC) { DST = __int_as_float((int)bperm(a32v, (unsigned)__float_as_int(SRC))); }
#endif

    // generic step: P = register-table prefix (cF/cB), SC = state var
#define STEPX(P, SC, PRE, POST, CADD) do { \
        float m0c = first_lane(SC) + (CADD); \
        float p   = __expf(SC + (PRE) - m0c); \
        float pn_ = DPPF(p, 0xB1); \
        unsigned W0 = pk_f16(p, pn_); \
        unsigned W1 = DPPU(W0, 0x4E); \
        unsigned W2 = DPPU(W0, 0x141); \
        unsigned W3 = DPPU(W1, 0x141); \
        unsigned W4 = DPPU(W0, 0x140); \
        unsigned W5 = DPPU(W1, 0x140); \
        unsigned W6 = DPPU(W4, 0x141); \
        unsigned W7 = DPPU(W5, 0x141); \
        float a0_ = 0.f, a1_ = 0.f, a2_ = 0.f, a3_ = 0.f; \
        a0_ = FDOT2(as_h2(W0), as_h2(P##0),  a0_); \
        a1_ = FDOT2(as_h2(W0), as_h2(P##8),  a1_); \
        a2_ = FDOT2(as_h2(W0), as_h2(P##16), a2_); \
        a3_ = FDOT2(as_h2(W0), as_h2(P##24), a3_); \
        a0_ = FDOT2(as_h2(W1), as_h2(P##1),  a0_); \
        a1_ = FDOT2(as_h2(W1), as_h2(P##9),  a1_); \
        a2_ = FDOT2(as_h2(W1), as_h2(P##17), a2_); \
        a3_ = FDOT2(as_h2(W1), as_h2(P##25), a3_); \
        a0_ = FDOT2(as_h2(W2), as_h2(P##2),  a0_); \
        a1_ = FDOT2(as_h2(W2), as_h2(P##10), a1_); \
        a2_ = FDOT2(as_h2(W2), as_h2(P##18), a2_); \
        a3_ = FDOT2(as_h2(W2), as_h2(P##26), a3_); \
        a0_ = FDOT2(as_h2(W3), as_h2(P##3),  a0_); \
        a1_ = FDOT2(as_h2(W3), as_h2(P##11), a1_); \
        a2_ = FDOT2(as_h2(W3), as_h2(P##19), a2_); \
        a3_ = FDOT2(as_h2(W3), as_h2(P##27), a3_); \
        a0_ = FDOT2(as_h2(W4), as_h2(P##4),  a0_); \
        a1_ = FDOT2(as_h2(W4), as_h2(P##12), a1_); \
        a2_ = FDOT2(as_h2(W4), as_h2(P##20), a2_); \
        a3_ = FDOT2(as_h2(W4), as_h2(P##28), a3_); \
        a0_ = FDOT2(as_h2(W5), as_h2(P##5),  a0_); \
        a1_ = FDOT2(as_h2(W5), as_h2(P##13), a1_); \
        a2_ = FDOT2(as_h2(W5), as_h2(P##21), a2_); \
        a3_ = FDOT2(as_h2(W5), as_h2(P##29), a3_); \
        a0_ = FDOT2(as_h2(W6), as_h2(P##6),  a0_); \
        a1_ = FDOT2(as_h2(W6), as_h2(P##14), a1_); \
        a2_ = FDOT2(as_h2(W6), as_h2(P##22), a2_); \
        a3_ = FDOT2(as_h2(W6), as_h2(P##30), a3_); \
        a0_ = FDOT2(as_h2(W7), as_h2(P##7),  a0_); \
        a1_ = FDOT2(as_h2(W7), as_h2(P##15), a1_); \
        a2_ = FDOT2(as_h2(W7), as_h2(P##23), a2_); \
        a3_ = FDOT2(as_h2(W7), as_h2(P##31), a3_); \
        float V0 = a0_ + swz16f(a1_); \
        float V1 = a2_ + swz16f(a3_); \
        float Vx; XCH32F(Vx, V1); \
        float sum_ = V0 + Vx; \
        SC = m0c + __logf(sum_) + (POST); \
    } while (0)

    // len for bwd mask (len in [256,512])
    float msum = 0.f;
    #pragma unroll
    for (int t = 0; t < 8; ++t) msum += mk[j + 64 * t];
    #pragma unroll
    for (int off = 32; off; off >>= 1) msum += __shfl_xor(msum, off);
    const int len = (int)(first_lane(msum) + 0.5f);

    // bootstrap both chains
    float scF = em[j] + trans[j * TSTRIDE + TT];   // score0 (mask[0]==1)
    float scB = trans[65 * TSTRIDE + j];           // u_511 = stop vector

    // emission rings, depth 8 each
    float rF0 = em[1 * TT + j], rF1 = em[2 * TT + j];
    float rF2 = em[3 * TT + j], rF3 = em[4 * TT + j];
    float rF4 = em[5 * TT + j], rF5 = em[6 * TT + j];
    float rF6 = em[7 * TT + j], rF7 = em[8 * TT + j];
    float rB0 = em[511 * TT + j], rB1 = em[510 * TT + j];
    float rB2 = em[509 * TT + j], rB3 = em[508 * TT + j];
    float rB4 = em[507 * TT + j], rB5 = em[506 * TT + j];
    float rB6 = em[505 * TT + j], rB7 = em[504 * TT + j];

    const float* peF = em + 9 * TT + j;
    const float* peB = em + 503 * TT + j;
    int scurB = 511;

#define BEE(RK, SV) (((SV) < len) ? (RK) : 0.0f)
#define STEPF(RK)       STEPX(cF, scF, 0.0f, (RK), 4.0f)
#define STEPB(RK, SV)   STEPX(cB, scB, BEE(RK, SV), 0.0f, 5.0f)

    // main: 31 iters x 8 step-pairs = fwd 1..248, bwd 511..264
    for (int it = 0; it < 31; ++it) {
        float nF0 = peF[0],   nF1 = peF[64],  nF2 = peF[128], nF3 = peF[192];
        float nF4 = peF[256], nF5 = peF[320], nF6 = peF[384], nF7 = peF[448];
        float nB0 = peB[0],    nB1 = peB[-64],  nB2 = peB[-128], nB3 = peB[-192];
        float nB4 = peB[-256], nB5 = peB[-320], nB6 = peB[-384], nB7 = peB[-448];
        peF += 512; peB -= 512;
        STEPF(rF0); STEPB(rB0, scurB - 0);
        STEPF(rF1); STEPB(rB1, scurB - 1);
        STEPF(rF2); STEPB(rB2, scurB - 2);
        STEPF(rF3); STEPB(rB3, scurB - 3);
        STEPF(rF4); STEPB(rB4, scurB - 4);
        STEPF(rF5); STEPB(rB5, scurB - 5);
        STEPF(rF6); STEPB(rB6, scurB - 6);
        STEPF(rF7); STEPB(rB7, scurB - 7);
        scurB -= 8;
        rF0 = nF0; rF1 = nF1; rF2 = nF2; rF3 = nF3;
        rF4 = nF4; rF5 = nF5; rF6 = nF6; rF7 = nF7;
        rB0 = nB0; rB1 = nB1; rB2 = nB2; rB3 = nB3;
        rB4 = nB4; rB5 = nB5; rB6 = nB6; rB7 = nB7;
    }
    // epilogue: fwd steps 249..255 (7), bwd steps 263..256 (8)
    STEPF(rF0); STEPB(rB0, 263);
    STEPF(rF1); STEPB(rB1, 262);
    STEPF(rF2); STEPB(rB2, 261);
    STEPF(rF3); STEPB(rB3, 260);
    STEPF(rF4); STEPB(rB4, 259);
    STEPF(rF5); STEPB(rB5, 258);
    STEPF(rF6); STEPB(rB6, 257);
    STEPB(rB7, 256);
#undef STEPF
#undef STEPB
#undef BEE
#undef STEPX
#undef XCH32F

    ws_state[(size_t)b * 128 + j] = scF;
    ws_state[(size_t)b * 128 + 64 + j] = scB;
}

// Per-batch wave: logZ = LSE_j(F[j]+U[j]), gold path, diff = logZ - gold.
__global__ __launch_bounds__(64) void crf_combine_kernel(
    const float* __restrict__ emissions,
    const int*   __restrict__ tags,
    const float* __restrict__ mask,
    const float* __restrict__ trans,
    const float* __restrict__ ws_state,
    float* __restrict__ diff_out)
{
    const int b = blockIdx.x;
    const int j = threadIdx.x;
    const float* em = emissions + (size_t)b * SS * TT;
    const float* mk = mask + (size_t)b * SS;

    float v = ws_state[(size_t)b * 128 + j] + ws_state[(size_t)b * 128 + 64 + j];
    float m = v;
    #pragma unroll
    for (int off = 32; off; off >>= 1) m = fmaxf(m, __shfl_xor(m, off));
    float e = __expf(v - m);
    #pragma unroll
    for (int off = 32; off; off >>= 1) e += __shfl_xor(e, off);
    float zres = m + __logf(e);

    float msum = 0.f;
    #pragma unroll
    for (int t = 0; t < 8; ++t) msum += mk[j + 64 * t];
    #pragma unroll
    for (int off = 32; off; off >>= 1) msum += __shfl_xor(msum, off);
    const int len = (int)(first_lane(msum) + 0.5f);

    const int* tg = tags + (size_t)b * SS;
    float acc = 0.f;
    for (int s = j; s < SS; s += 64) {
        if (s < len) {
            if (s > 0) {
                int curr = tg[s], prev = tg[s - 1];
                acc += trans[curr * TSTRIDE + prev] + em[s * TT + curr];
            } else {
                int t0_ = tg[0];
                acc += em[t0_] + trans[t0_ * TSTRIDE + TT];
            }
        }
    }
    #pragma unroll
    for (int off = 32; off; off >>= 1) acc += __shfl_xor(acc, off);
    if (j == 0) {
        int last = tg[len - 1];
        acc += trans[65 * TSTRIDE + last];
        diff_out[b] = zres - acc;
    }
}

__global__ __launch_bounds__(256) void crf_final_kernel(
    const float* __restrict__ diff,
    float* __restrict__ out)
{
    __shared__ float sdata[4];
    int t = threadIdx.x;
    float v = 0.f;
    for (int i = t; i < BB; i += 256) v += diff[i];
    #pragma unroll
    for (int off = 32; off; off >>= 1) v += __shfl_xor(v, off);
    if ((t & 63) == 0) sdata[t >> 6] = v;
    __syncthreads();
    if (t == 0) out[0] = (sdata[0] + sdata[1] + sdata[2] + sdata[3]) * (1.0f / BB);
}

extern "C" void kernel_launch(void* const* d_in, const int* in_sizes, int n_in,
                              void* d_out, int out_size, void* d_ws, size_t ws_size,
                              hipStream_t stream) {
    const float* emissions = (const float*)d_in[0];
    const int*   tags      = (const int*)d_in[1];
    const float* mask      = (const float*)d_in[2];
    const float* trans     = (const float*)d_in[3];
    float* out  = (float*)d_out;
    float* ws_state = (float*)d_ws;             // 512*128 floats
    float* diff = ws_state + (size_t)BB * 128;  // 512 floats

    crf_scan_dual_kernel<<<BB, 64, 0, stream>>>(emissions, mask, trans, ws_state);
    crf_combine_kernel<<<BB, 64, 0, stream>>>(emissions, tags, mask, trans,
                                              ws_state, diff);
    crf_final_kernel<<<1, 256, 0, stream>>>(diff, out);
}

// Round 15
// 61.842 us; speedup vs baseline: 3.1210x; 1.6536x over previous
//
#include <hip/hip_runtime.h>

#define BB 512
#define SS 512
#define TT 64
#define TSTRIDE 66   // transitions is (66,66)

typedef _Float16 h2 __attribute__((ext_vector_type(2)));
typedef int i2v __attribute__((ext_vector_type(2)));

static __device__ __forceinline__ float first_lane(float v) {
    return __int_as_float(__builtin_amdgcn_readfirstlane(__float_as_int(v)));
}
static __device__ __forceinline__ unsigned pk_f16(float a, float b) {
    return __builtin_bit_cast(unsigned, __builtin_amdgcn_cvt_pkrtz(a, b));
}
static __device__ __forceinline__ h2 as_h2(unsigned u) {
    return __builtin_bit_cast(h2, u);
}
static __device__ __forceinline__ unsigned bperm(int addr, unsigned v) {
    return (unsigned)__builtin_amdgcn_ds_bpermute(addr, (int)v);
}
static __device__ __forceinline__ float swz16f(float v) {   // value from lane^16
    return __int_as_float(__builtin_amdgcn_ds_swizzle(__float_as_int(v), 0x401F));
}
#define FDOT2(a, b, c) __builtin_amdgcn_fdot2((a), (b), (c), false)
#define DPPF(v, ctrl) __int_as_float(__builtin_amdgcn_mov_dpp(__float_as_int(v), (ctrl), 0xF, 0xF, true))
#define DPPU(v, ctrl) ((unsigned)__builtin_amdgcn_mov_dpp((int)(v), (ctrl), 0xF, 0xF, true))

#define DO32(F) F(0) F(1) F(2) F(3) F(4) F(5) F(6) F(7) \
                F(8) F(9) F(10) F(11) F(12) F(13) F(14) F(15) \
                F(16) F(17) F(18) F(19) F(20) F(21) F(22) F(23) \
                F(24) F(25) F(26) F(27) F(28) F(29) F(30) F(31)

// R15 = R9 MITM structure + R11 blocked dots + R8 product-form recurrence +
// pure-VALU reduce (permlane16_swap/permlane32_swap).
// State t = exp(score - anchor); per step: pack t -> DPP tree (verified
// tl={0,2,7,5,15,13,8,10}) -> 32 fdot2 -> reduce (perm16, perm32) -> sum;
// t' = (sum * g) * rcp(s0); side chains: L2 += log2(s0), Lc += e0+4 where
// g = exp(ee - e0 - 4) precomputed from the emission ring (exp/log are OFF
// the critical path). Anchor reconstruction at the end (R8-verified).
__global__ __launch_bounds__(64)
__attribute__((amdgpu_waves_per_eu(1, 1)))
void crf_scan2_kernel(
    const float* __restrict__ emissions,   // [B,S,T]
    const float* __restrict__ mask,        // [B,S]
    const float* __restrict__ trans,       // [66,66]
    float* __restrict__ ws_state)          // [B][128]: F[64] then U[64]
{
    __shared__ unsigned EQ[32][64];        // 8 KB E-fragment staging

    const int blk = blockIdx.x;
    const int b   = blk >> 1;
    const int dir = blk & 1;
    const int j   = threadIdx.x;   // 0..63
    const bool lo32  = (j < 32);
    const bool odd16 = (j & 16) != 0;
    const int a32v = ((j ^ 32) << 2);      // bpermute fallback address

    const float* em = emissions + (size_t)b * SS * TT;
    const float* mk = mask + (size_t)b * SS;

    // ---- E fragments, pre-permuted for the blocked scheme (R11 verified) --
    {
        const int tl[8] = {0, 2, 7, 5, 15, 13, 8, 10};
        #pragma unroll
        for (int w = 0; w < 32; ++w) {
            int m = w >> 3, k = w & 7;
            int y0 = j ^ tl[k];
            int y1 = y0 ^ 1;
            int x  = j ^ (m << 4);
            if (dir == 0)   // fwd: M[x][y] = trans[y*66 + x]
                EQ[w][j] = pk_f16(__expf(trans[y0 * TSTRIDE + x]),
                                  __expf(trans[y1 * TSTRIDE + x]));
            else            // bwd: M[x][y] = trans[x*66 + y]
                EQ[w][j] = pk_f16(__expf(trans[x * TSTRIDE + y0]),
                                  __expf(trans[x * TSTRIDE + y1]));
        }
    }
    __syncthreads();

#define CDECL(K) const unsigned c##K = EQ[K][j];
    DO32(CDECL)
#undef CDECL

#if defined(__has_builtin) && __has_builtin(__builtin_amdgcn_permlane32_swap)
#define XCH32F(DST, SRC) { i2v r_ = __builtin_amdgcn_permlane32_swap( \
                               __float_as_int(SRC), __float_as_int(SRC), false, false); \
                           DST = __int_as_float(lo32 ? r_.y : r_.x); }
#else
#define XCH32F(DST, SRC) { DST = __int_as_float((int)bperm(a32v, (unsigned)__float_as_int(SRC))); }
#endif

#if defined(__has_builtin) && __has_builtin(__builtin_amdgcn_permlane16_swap)
// odd-16-rows(vdst) <-> even-16-rows(src); with both = x: x[l^16] = odd16 ? .x : .y
#define XCH16F(DST, SRC) { i2v r_ = __builtin_amdgcn_permlane16_swap( \
                               __float_as_int(SRC), __float_as_int(SRC), false, false); \
                           DST = __int_as_float(odd16 ? r_.x : r_.y); }
#else
#define XCH16F(DST, SRC) { DST = swz16f(SRC); }
#endif

    float t, L2 = 0.f, Lc = 0.f;

#define STEPP(GK) do { \
        float pn_ = DPPF(t, 0xB1); \
        unsigned W0 = pk_f16(t, pn_); \
        unsigned W1 = DPPU(W0, 0x4E); \
        unsigned W2 = DPPU(W0, 0x141); \
        unsigned W3 = DPPU(W1, 0x141); \
        unsigned W4 = DPPU(W0, 0x140); \
        unsigned W5 = DPPU(W1, 0x140); \
        unsigned W6 = DPPU(W4, 0x141); \
        unsigned W7 = DPPU(W5, 0x141); \
        float a0_ = 0.f, a1_ = 0.f, a2_ = 0.f, a3_ = 0.f; \
        a0_ = FDOT2(as_h2(W0), as_h2(c0),  a0_); \
        a1_ = FDOT2(as_h2(W0), as_h2(c8),  a1_); \
        a2_ = FDOT2(as_h2(W0), as_h2(c16), a2_); \
        a3_ = FDOT2(as_h2(W0), as_h2(c24), a3_); \
        a0_ = FDOT2(as_h2(W1), as_h2(c1),  a0_); \
        a1_ = FDOT2(as_h2(W1), as_h2(c9),  a1_); \
        a2_ = FDOT2(as_h2(W1), as_h2(c17), a2_); \
        a3_ = FDOT2(as_h2(W1), as_h2(c25), a3_); \
        a0_ = FDOT2(as_h2(W2), as_h2(c2),  a0_); \
        a1_ = FDOT2(as_h2(W2), as_h2(c10), a1_); \
        a2_ = FDOT2(as_h2(W2), as_h2(c18), a2_); \
        a3_ = FDOT2(as_h2(W2), as_h2(c26), a3_); \
        a0_ = FDOT2(as_h2(W3), as_h2(c3),  a0_); \
        a1_ = FDOT2(as_h2(W3), as_h2(c11), a1_); \
        a2_ = FDOT2(as_h2(W3), as_h2(c19), a2_); \
        a3_ = FDOT2(as_h2(W3), as_h2(c27), a3_); \
        a0_ = FDOT2(as_h2(W4), as_h2(c4),  a0_); \
        a1_ = FDOT2(as_h2(W4), as_h2(c12), a1_); \
        a2_ = FDOT2(as_h2(W4), as_h2(c20), a2_); \
        a3_ = FDOT2(as_h2(W4), as_h2(c28), a3_); \
        a0_ = FDOT2(as_h2(W5), as_h2(c5),  a0_); \
        a1_ = FDOT2(as_h2(W5), as_h2(c13), a1_); \
        a2_ = FDOT2(as_h2(W5), as_h2(c21), a2_); \
        a3_ = FDOT2(as_h2(W5), as_h2(c29), a3_); \
        a0_ = FDOT2(as_h2(W6), as_h2(c6),  a0_); \
        a1_ = FDOT2(as_h2(W6), as_h2(c14), a1_); \
        a2_ = FDOT2(as_h2(W6), as_h2(c22), a2_); \
        a3_ = FDOT2(as_h2(W6), as_h2(c30), a3_); \
        a0_ = FDOT2(as_h2(W7), as_h2(c7),  a0_); \
        a1_ = FDOT2(as_h2(W7), as_h2(c15), a1_); \
        a2_ = FDOT2(as_h2(W7), as_h2(c23), a2_); \
        a3_ = FDOT2(as_h2(W7), as_h2(c31), a3_); \
        float a1x_, a3x_; \
        XCH16F(a1x_, a1_) \
        XCH16F(a3x_, a3_) \
        float V0 = a0_ + a1x_; \
        float V1 = a2_ + a3x_; \
        float Vx; XCH32F(Vx, V1); \
        float sum_ = V0 + Vx; \
        float s0_ = first_lane(sum_); \
        L2 += __log2f(s0_); \
        t = (sum_ * (GK)) * __builtin_amdgcn_rcpf(s0_); \
    } while (0)

#define GPREPF(RK, GOUT) { float e0_ = first_lane(RK); \
                           GOUT = __expf((RK) - e0_ - 4.0f); Lc += e0_ + 4.0f; }
#define GPREPB(RK, SV, GOUT) { float ee_ = ((SV) < len) ? (RK) : 0.0f; \
                               float e0_ = first_lane(ee_); \
                               GOUT = __expf(ee_ - e0_ - 4.0f); Lc += e0_ + 4.0f; }

    const float LN2 = 0.69314718055994531f;

    if (dir == 0) {
        // ---------- forward: steps 1..255 (unmasked; len >= 256) ----------
        float sc0 = em[j] + trans[j * TSTRIDE + TT];   // mask[0]==1 always
        const float m0c0 = first_lane(sc0) + 4.0f;
        t = __expf(sc0 - m0c0);

        float r0 = em[1 * TT + j], r1 = em[2 * TT + j];
        float r2 = em[3 * TT + j], r3 = em[4 * TT + j];
        float r4 = em[5 * TT + j], r5 = em[6 * TT + j];
        float r6 = em[7 * TT + j], r7 = em[8 * TT + j];
        const float* pe = em + 9 * TT + j;
        for (int it = 0; it < 31; ++it) {       // steps 1..248
            float n0 = pe[0],   n1 = pe[64],  n2 = pe[128], n3 = pe[192];
            float n4 = pe[256], n5 = pe[320], n6 = pe[384], n7 = pe[448];
            pe += 512;
            float g0, g1, g2, g3, g4, g5, g6, g7;
            GPREPF(r0, g0) GPREPF(r1, g1) GPREPF(r2, g2) GPREPF(r3, g3)
            GPREPF(r4, g4) GPREPF(r5, g5) GPREPF(r6, g6) GPREPF(r7, g7)
            STEPP(g0); STEPP(g1); STEPP(g2); STEPP(g3);
            STEPP(g4); STEPP(g5); STEPP(g6); STEPP(g7);
            r0 = n0; r1 = n1; r2 = n2; r3 = n3;
            r4 = n4; r5 = n5; r6 = n6; r7 = n7;
        }
        {   // steps 249..255 (7 steps, rings r0..r6)
            float g0, g1, g2, g3, g4, g5, g6;
            GPREPF(r0, g0) GPREPF(r1, g1) GPREPF(r2, g2) GPREPF(r3, g3)
            GPREPF(r4, g4) GPREPF(r5, g5) GPREPF(r6, g6)
            STEPP(g0); STEPP(g1); STEPP(g2); STEPP(g3);
            STEPP(g4); STEPP(g5); STEPP(g6);
        }
        ws_state[(size_t)b * 128 + j] = m0c0 + Lc + L2 * LN2 + __logf(t);
    } else {
        // ---------- backward: steps 511..256 ----------
        float msum = 0.f;
        #pragma unroll
        for (int tq = 0; tq < 8; ++tq) msum += mk[j + 64 * tq];
        #pragma unroll
        for (int off = 32; off; off >>= 1) msum += __shfl_xor(msum, off);
        const int len = (int)(first_lane(msum) + 0.5f);   // in [256,512]

        float u0 = trans[65 * TSTRIDE + j];               // u_511 = stop vector
        const float anc0 = first_lane(u0) + 4.0f;
        float q = __expf(u0 - anc0);

        float r0 = em[511 * TT + j], r1 = em[510 * TT + j];
        float r2 = em[509 * TT + j], r3 = em[508 * TT + j];
        float r4 = em[507 * TT + j], r5 = em[506 * TT + j];
        float r6 = em[505 * TT + j], r7 = em[504 * TT + j];
        const float* pe = em + 503 * TT + j;
        int scur = 511;

        // init: fold h@511 (STEP@p post-multiplies h@(p-1))
        {
            float h0i;
            GPREPB(r0, 511, h0i)
            t = q * h0i;
        }
        for (int it = 0; it < 31; ++it) {       // steps 511..264
            float n0 = pe[0],    n1 = pe[-64],  n2 = pe[-128], n3 = pe[-192];
            float n4 = pe[-256], n5 = pe[-320], n6 = pe[-384], n7 = pe[-448];
            pe -= 512;
            float g1, g2, g3, g4, g5, g6, g7, g8;
            GPREPB(r1, scur - 1, g1) GPREPB(r2, scur - 2, g2)
            GPREPB(r3, scur - 3, g3) GPREPB(r4, scur - 4, g4)
            GPREPB(r5, scur - 5, g5) GPREPB(r6, scur - 6, g6)
            GPREPB(r7, scur - 7, g7) GPREPB(n0, scur - 8, g8)
            STEPP(g1); STEPP(g2); STEPP(g3); STEPP(g4);
            STEPP(g5); STEPP(g6); STEPP(g7); STEPP(g8);
            scur -= 8;
            r0 = n0; r1 = n1; r2 = n2; r3 = n3;
            r4 = n4; r5 = n5; r6 = n6; r7 = n7;
        }
        {   // steps 263..256 (rings r0..r7 = rows 263..256)
            float g1, g2, g3, g4, g5, g6, g7;
            GPREPB(r1, 262, g1) GPREPB(r2, 261, g2) GPREPB(r3, 260, g3)
            GPREPB(r4, 259, g4) GPREPB(r5, 258, g5) GPREPB(r6, 257, g6)
            GPREPB(r7, 256, g7)
            STEPP(g1); STEPP(g2); STEPP(g3); STEPP(g4);
            STEPP(g5); STEPP(g6); STEPP(g7); STEPP(1.0f);
        }
        ws_state[(size_t)b * 128 + 64 + j] = anc0 + Lc + L2 * LN2 + __logf(t);
    }
#undef STEPP
#undef GPREPF
#undef GPREPB
#undef XCH32F
#undef XCH16F
}

// Per-batch wave: logZ = LSE_j(F[j]+U[j]), gold path, diff = logZ - gold.
__global__ __launch_bounds__(64) void crf_combine_kernel(
    const float* __restrict__ emissions,
    const int*   __restrict__ tags,
    const float* __restrict__ mask,
    const float* __restrict__ trans,
    const float* __restrict__ ws_state,
    float* __restrict__ diff_out)
{
    const int b = blockIdx.x;
    const int j = threadIdx.x;
    const float* em = emissions + (size_t)b * SS * TT;
    const float* mk = mask + (size_t)b * SS;

    float v = ws_state[(size_t)b * 128 + j] + ws_state[(size_t)b * 128 + 64 + j];
    float m = v;
    #pragma unroll
    for (int off = 32; off; off >>= 1) m = fmaxf(m, __shfl_xor(m, off));
    float e = __expf(v - m);
    #pragma unroll
    for (int off = 32; off; off >>= 1) e += __shfl_xor(e, off);
    float zres = m + __logf(e);

    float msum = 0.f;
    #pragma unroll
    for (int t = 0; t < 8; ++t) msum += mk[j + 64 * t];
    #pragma unroll
    for (int off = 32; off; off >>= 1) msum += __shfl_xor(msum, off);
    const int len = (int)(first_lane(msum) + 0.5f);

    const int* tg = tags + (size_t)b * SS;
    float acc = 0.f;
    for (int s = j; s < SS; s += 64) {
        if (s < len) {
            if (s > 0) {
                int curr = tg[s], prev = tg[s - 1];
                acc += trans[curr * TSTRIDE + prev] + em[s * TT + curr];
            } else {
                int t0_ = tg[0];
                acc += em[t0_] + trans[t0_ * TSTRIDE + TT];
            }
        }
    }
    #pragma unroll
    for (int off = 32; off; off >>= 1) acc += __shfl_xor(acc, off);
    if (j == 0) {
        int last = tg[len - 1];
        acc += trans[65 * TSTRIDE + last];
        diff_out[b] = zres - acc;
    }
}

__global__ __launch_bounds__(256) void crf_final_kernel(
    const float* __restrict__ diff,
    float* __restrict__ out)
{
    __shared__ float sdata[4];
    int t = threadIdx.x;
    float v = 0.f;
    for (int i = t; i < BB; i += 256) v += diff[i];
    #pragma unroll
    for (int off = 32; off; off >>= 1) v += __shfl_xor(v, off);
    if ((t & 63) == 0) sdata[t >> 6] = v;
    __syncthreads();
    if (t == 0) out[0] = (sdata[0] + sdata[1] + sdata[2] + sdata[3]) * (1.0f / BB);
}

extern "C" void kernel_launch(void* const* d_in, const int* in_sizes, int n_in,
                              void* d_out, int out_size, void* d_ws, size_t ws_size,
                              hipStream_t stream) {
    const float* emissions = (const float*)d_in[0];
    const int*   tags      = (const int*)d_in[1];
    const float* mask      = (const float*)d_in[2];
    const float* trans     = (const float*)d_in[3];
    float* out  = (float*)d_out;
    float* ws_state = (float*)d_ws;             // 512*128 floats
    float* diff = ws_state + (size_t)BB * 128;  // 512 floats

    crf_scan2_kernel<<<2 * BB, 64, 0, stream>>>(emissions, mask, trans, ws_state);
    crf_combine_kernel<<<BB, 64, 0, stream>>>(emissions, tags, mask, trans,
                                              ws_state, diff);
    crf_final_kernel<<<1, 256, 0, stream>>>(diff, out);
}